// Round 5
// baseline (3299.459 us; speedup 1.0000x reference)
//
#include <hip/hip_runtime.h>
#include <hip/hip_bf16.h>
#include <stdint.h>

#define BATCH  64
#define SEQ    1024
#define EMBED  128
#define HIDDEN 512
#define VOCAB  256

using bf16 = __hip_bfloat16;
typedef __attribute__((ext_vector_type(8))) short bf16x8;
typedef __attribute__((ext_vector_type(4))) float f32x4;

__device__ __forceinline__ float bfu(unsigned short u) {
    return __uint_as_float(((unsigned)u) << 16);
}

// ---------------- weight converts ----------------
__global__ void k_cvt(const float* __restrict__ in, bf16* __restrict__ out, int n) {
    int i = blockIdx.x * 256 + threadIdx.x;
    if (i < n) out[i] = __float2bfloat16(in[i]);
}

// W_xh [EMBED][HIDDEN] -> wxh_t [HIDDEN][EMBED] bf16
__global__ void k_txp_wxh(const float* __restrict__ in, bf16* __restrict__ out) {
    int idx = blockIdx.x * 256 + threadIdx.x;   // 65536
    int e = idx >> 9, j = idx & 511;
    out[j * EMBED + e] = __float2bfloat16(in[idx]);
}

// W_hh [K=512][N=512] -> wt [N=512][K=512] bf16
__global__ void k_txp_whh(const float* __restrict__ in, bf16* __restrict__ out) {
    int idx = blockIdx.x * 256 + threadIdx.x;   // 262144
    int k = idx >> 9, n = idx & 511;
    out[n * HIDDEN + k] = __float2bfloat16(in[idx]);
}

// ---------------- bf16 MFMA GEMM:  C[M][N] = A[M][K] * B'[N][K]^T + bias ----------------
// PERMUTE (phase-1 only): write C in the scan's per-thread-contiguous layout:
//   elem(row=t*64+b, col) -> xwp[(t*4+blk)*8192 + (wid*64 + lk*16 + lm)*16 + nt*4 + r]
//   blk=b>>4, lk=(b&15)>>2, r=b&3, wid=col>>6, nt=(col>>4)&3, lm=col&15
template<bool GATHER, bool OUT_BF16, bool PERMUTE>
__global__ __launch_bounds__(256) void k_gemm(
    const bf16* __restrict__ A,       // [M][K]; if GATHER: embedding table [VOCAB][K]
    const int*  __restrict__ xtok,    // tokens [BATCH][SEQ] (GATHER only)
    const bf16* __restrict__ B,       // [N][K]
    const float* __restrict__ bias,   // [N]
    float* __restrict__ Cf,
    bf16*  __restrict__ Cb,
    int M, int N, int K)
{
    __shared__ bf16 As[64][72];
    __shared__ bf16 Bs[64][72];
    const int m0 = blockIdx.x * 64, n0 = blockIdx.y * 64;
    const int tid  = threadIdx.x;
    const int lane = tid & 63, wid = tid >> 6;
    const int wm = wid >> 1, wn = wid & 1;
    const int lrow = tid >> 3, lc8 = tid & 7;

    f32x4 acc[2][2] = {};

    for (int k0 = 0; k0 < K; k0 += 64) {
#pragma unroll
        for (int pass = 0; pass < 2; ++pass) {
            int row = pass * 32 + lrow;
            const bf16* asrc;
            if (GATHER) {
                int m = m0 + row;                 // m = t*BATCH + b
                int t = m >> 6, bb = m & 63;
                int tok = xtok[bb * SEQ + t];
                asrc = A + (size_t)tok * K + k0 + lc8 * 8;
            } else {
                asrc = A + (size_t)(m0 + row) * K + k0 + lc8 * 8;
            }
            *reinterpret_cast<uint4*>(&As[row][lc8 * 8]) = *reinterpret_cast<const uint4*>(asrc);
            *reinterpret_cast<uint4*>(&Bs[row][lc8 * 8]) =
                *reinterpret_cast<const uint4*>(B + (size_t)(n0 + row) * K + k0 + lc8 * 8);
        }
        __syncthreads();
#pragma unroll
        for (int kk = 0; kk < 2; ++kk) {
            bf16x8 af[2], bg[2];
#pragma unroll
            for (int mt = 0; mt < 2; ++mt)
                af[mt] = *reinterpret_cast<const bf16x8*>(
                    &As[wm * 32 + mt * 16 + (lane & 15)][kk * 32 + (lane >> 4) * 8]);
#pragma unroll
            for (int nt = 0; nt < 2; ++nt)
                bg[nt] = *reinterpret_cast<const bf16x8*>(
                    &Bs[wn * 32 + nt * 16 + (lane & 15)][kk * 32 + (lane >> 4) * 8]);
#pragma unroll
            for (int mt = 0; mt < 2; ++mt)
#pragma unroll
                for (int nt = 0; nt < 2; ++nt)
                    acc[mt][nt] = __builtin_amdgcn_mfma_f32_16x16x32_bf16(
                        af[mt], bg[nt], acc[mt][nt], 0, 0, 0);
        }
        __syncthreads();
    }
    if (PERMUTE) {
        const int t = m0 >> 6, wid_s = n0 >> 6;
#pragma unroll
        for (int mt = 0; mt < 2; ++mt) {
            int blk = wm * 2 + mt;
            bf16 tmp[8];
#pragma unroll
            for (int nt = 0; nt < 2; ++nt) {
                int col = n0 + wn * 32 + nt * 16 + (lane & 15);
                float bv = bias[col];
#pragma unroll
                for (int r = 0; r < 4; ++r)
                    tmp[nt * 4 + r] = __float2bfloat16(acc[mt][nt][r] + bv);
            }
            size_t off = (((size_t)(t * 4 + blk) * 512) + wid_s * 64 + lane) * 16 + wn * 8;
            *reinterpret_cast<uint4*>(Cb + off) = *reinterpret_cast<uint4*>(tmp);
        }
    } else {
#pragma unroll
        for (int mt = 0; mt < 2; ++mt) {
            int rbase = m0 + wm * 32 + mt * 16 + (lane >> 4) * 4;
#pragma unroll
            for (int nt = 0; nt < 2; ++nt) {
                int col = n0 + wn * 32 + nt * 16 + (lane & 15);
                float bv = bias[col];
#pragma unroll
                for (int r = 0; r < 4; ++r) {
                    float v = acc[mt][nt][r] + bv;
                    size_t off = (size_t)(rbase + r) * N + col;
                    if (OUT_BF16) Cb[off] = __float2bfloat16(v);
                    else          Cf[off] = v;
                }
            }
        }
    }
}

// ---------------- MFMA scan: 4 blocks x 16 batch rows ----------------
// 16 k-chunks of 32: 0..2 LDS-resident, 3..10 register-resident (asm-pinned,
// non-rematerializable), 11..15 streamed from L2 (164 KB/step).
#define ROWS 16
#define CHK_LDS 3
#define CHK_REG 8
#define WRES_STRIDE (CHK_LDS * 32 + 8)   // 104
#define H_STRIDE (HIDDEN + 8)            // 520

__global__ __launch_bounds__(512, 2) void k_scan_mfma(
    const bf16* __restrict__ xwp,   // permuted [SEQ][4][512 tid][16]
    const bf16* __restrict__ wt,    // [HIDDEN n][HIDDEN k]
    const float* __restrict__ h0,   // [BATCH][HIDDEN]
    bf16* __restrict__ hh,          // [BATCH][SEQ][HIDDEN]
    float* __restrict__ hfin)       // [BATCH][HIDDEN]
{
    __shared__ bf16 wres[HIDDEN * WRES_STRIDE];   // 106.5 KB
    __shared__ bf16 h_lds[2][ROWS * H_STRIDE];    // 2 x 16.6 KB

    const int tid  = threadIdx.x;
    const int lane = tid & 63, wid = tid >> 6;
    const int b0   = blockIdx.x * ROWS;
    const int scol = wid * 64;
    const int lm   = lane & 15, lk = lane >> 4;

    // ---- one-time: LDS-resident W chunk rows ----
    {
        const bf16* src = wt + (size_t)tid * HIDDEN;
        bf16* dst = &wres[tid * WRES_STRIDE];
#pragma unroll
        for (int j = 0; j < (CHK_LDS * 32) / 8; ++j)
            *reinterpret_cast<uint4*>(dst + j * 8) =
                *reinterpret_cast<const uint4*>(src + j * 8);
    }
    // ---- one-time: h0 -> h_lds[0] ----
    {
        int row = tid >> 5, c = (tid & 31) * 16;
        const float* src = h0 + (size_t)(b0 + row) * HIDDEN + c;
        bf16 tmp[16];
#pragma unroll
        for (int j = 0; j < 16; ++j) tmp[j] = __float2bfloat16(src[j]);
        *reinterpret_cast<uint4*>(&h_lds[0][row * H_STRIDE + c])     = *reinterpret_cast<uint4*>(&tmp[0]);
        *reinterpret_cast<uint4*>(&h_lds[0][row * H_STRIDE + c + 8]) = *reinterpret_cast<uint4*>(&tmp[8]);
    }

    // ---- one-time: register-resident B fragments, pinned against remat ----
    bf16x8 breg[CHK_REG][4];
#pragma unroll
    for (int c = 0; c < CHK_REG; ++c)
#pragma unroll
        for (int nt = 0; nt < 4; ++nt) {
            breg[c][nt] = *reinterpret_cast<const bf16x8*>(
                wt + (size_t)(scol + nt * 16 + lm) * HIDDEN + (CHK_LDS + c) * 32 + lk * 8);
            asm volatile("" : "+v"(breg[c][nt]));   // opaque: cannot be rematerialized
        }

    const bf16* grow[4];
    const bf16* lrowp[4];
#pragma unroll
    for (int nt = 0; nt < 4; ++nt) {
        int row = scol + nt * 16 + lm;
        grow[nt]  = wt + (size_t)row * HIDDEN + lk * 8;
        lrowp[nt] = &wres[row * WRES_STRIDE + lk * 8];
    }

    const int srow = tid >> 5, sc = (tid & 31) * 16;   // hh store slots

    __syncthreads();

    int p = 0;
    for (int t = 0; t < SEQ; ++t) {
        // store h(t-1) -> hh (vectorized; reads h_lds[p], complete since last barrier)
        if (t > 0) {
            uint4 v0 = *reinterpret_cast<const uint4*>(&h_lds[p][srow * H_STRIDE + sc]);
            uint4 v1 = *reinterpret_cast<const uint4*>(&h_lds[p][srow * H_STRIDE + sc + 8]);
            bf16* dst = hh + ((size_t)(b0 + srow) * SEQ + (t - 1)) * HIDDEN + sc;
            *reinterpret_cast<uint4*>(dst)     = v0;
            *reinterpret_cast<uint4*>(dst + 8) = v1;
        }

        // xw for this step: one contiguous 32B block per thread (permuted layout)
        ushort xe[16];
        {
            const uint4* xp = reinterpret_cast<const uint4*>(xwp) +
                              ((size_t)(t * 4 + blockIdx.x) * 512 + tid) * 2;
            *reinterpret_cast<uint4*>(&xe[0]) = xp[0];
            *reinterpret_cast<uint4*>(&xe[8]) = xp[1];
        }

        f32x4 acc[4] = {};
#pragma unroll
        for (int kc = 0; kc < 16; ++kc) {
            bf16x8 af = *reinterpret_cast<const bf16x8*>(
                &h_lds[p][lm * H_STRIDE + kc * 32 + lk * 8]);
#pragma unroll
            for (int nt = 0; nt < 4; ++nt) {
                bf16x8 bg;
                if (kc < CHK_LDS)
                    bg = *reinterpret_cast<const bf16x8*>(lrowp[nt] + kc * 32);
                else if (kc < CHK_LDS + CHK_REG)
                    bg = breg[kc - CHK_LDS][nt];
                else
                    bg = *reinterpret_cast<const bf16x8*>(grow[nt] + kc * 32);
                acc[nt] = __builtin_amdgcn_mfma_f32_16x16x32_bf16(af, bg, acc[nt], 0, 0, 0);
            }
        }

        // epilogue: h_new -> other h buffer (D map: col=lane&15, row=(lane>>4)*4+r)
#pragma unroll
        for (int nt = 0; nt < 4; ++nt) {
            int col = scol + nt * 16 + lm;
#pragma unroll
            for (int r = 0; r < 4; ++r) {
                int m = lk * 4 + r;
                float pre = acc[nt][r] + bfu(xe[nt * 4 + r]);
                float e2  = __expf(2.f * pre);
                float hn  = 1.f - 2.f / (e2 + 1.f);     // tanh(pre)
                h_lds[p ^ 1][m * H_STRIDE + col] = __float2bfloat16(hn);
                if (t == SEQ - 1) hfin[(size_t)(b0 + m) * HIDDEN + col] = hn;
            }
        }
        p ^= 1;
        __syncthreads();    // single barrier per step
    }

    // final hh row store: h(SEQ-1) lives in h_lds[p]
    {
        uint4 v0 = *reinterpret_cast<const uint4*>(&h_lds[p][srow * H_STRIDE + sc]);
        uint4 v1 = *reinterpret_cast<const uint4*>(&h_lds[p][srow * H_STRIDE + sc + 8]);
        bf16* dst = hh + ((size_t)(b0 + srow) * SEQ + (SEQ - 1)) * HIDDEN + sc;
        *reinterpret_cast<uint4*>(dst)     = v0;
        *reinterpret_cast<uint4*>(dst + 8) = v1;
    }
}

// ---------------- launch ----------------
extern "C" void kernel_launch(void* const* d_in, const int* in_sizes, int n_in,
                              void* d_out, int out_size, void* d_ws, size_t ws_size,
                              hipStream_t stream) {
    const int*   x    = (const int*)  d_in[0];
    const float* h0   = (const float*)d_in[1];
    const float* emb  = (const float*)d_in[2];
    const float* wxh  = (const float*)d_in[3];
    const float* whh  = (const float*)d_in[4];
    const float* bh   = (const float*)d_in[5];
    const float* whyw = (const float*)d_in[6];
    const float* whyb = (const float*)d_in[7];

    float* logits = (float*)d_out;                            // [BATCH][SEQ][VOCAB]
    float* hfin   = logits + (size_t)BATCH * SEQ * VOCAB;     // [BATCH][HIDDEN]

    char* p = (char*)d_ws;
    bf16* xwp    = (bf16*)p; p += (size_t)SEQ * BATCH * HIDDEN * 2;
    bf16* hh     = (bf16*)p; p += (size_t)BATCH * SEQ * HIDDEN * 2;
    bf16* wt     = (bf16*)p; p += (size_t)HIDDEN * HIDDEN * 2;
    bf16* wxh_t  = (bf16*)p; p += (size_t)HIDDEN * EMBED * 2;
    bf16* emb_bf = (bf16*)p; p += (size_t)VOCAB * EMBED * 2;
    bf16* why_bf = (bf16*)p; p += (size_t)VOCAB * HIDDEN * 2;

    k_txp_whh<<<(HIDDEN * HIDDEN + 255) / 256, 256, 0, stream>>>(whh, wt);
    k_cvt<<<(VOCAB * EMBED + 255) / 256, 256, 0, stream>>>(emb, emb_bf, VOCAB * EMBED);
    k_cvt<<<(VOCAB * HIDDEN + 255) / 256, 256, 0, stream>>>(whyw, why_bf, VOCAB * HIDDEN);
    k_txp_wxh<<<(EMBED * HIDDEN + 255) / 256, 256, 0, stream>>>(wxh, wxh_t);

    // phase 1: xwp = permute(emb[x] @ W_xh + b_h)
    k_gemm<true, true, true><<<dim3((SEQ * BATCH) / 64, HIDDEN / 64), 256, 0, stream>>>(
        emb_bf, x, wxh_t, bh, nullptr, xwp, SEQ * BATCH, HIDDEN, EMBED);

    // phase 2: the recurrence (4 blocks x 16 batch rows)
    k_scan_mfma<<<BATCH / ROWS, 512, 0, stream>>>(xwp, wt, h0, hh, hfin);

    // phase 3: logits = hh @ W_hy^T + b
    k_gemm<false, false, false><<<dim3((BATCH * SEQ) / 64, VOCAB / 64), 256, 0, stream>>>(
        hh, nullptr, why_bf, whyb, logits, nullptr, BATCH * SEQ, VOCAB, HIDDEN);
}

// Round 6
// 2938.797 us; speedup vs baseline: 1.1227x; 1.1227x over previous
//
#include <hip/hip_runtime.h>
#include <hip/hip_bf16.h>
#include <stdint.h>

#define BATCH  64
#define SEQ    1024
#define EMBED  128
#define HIDDEN 512
#define VOCAB  256

using bf16 = __hip_bfloat16;
typedef __attribute__((ext_vector_type(8))) short bf16x8;
typedef __attribute__((ext_vector_type(4))) float f32x4;

__device__ __forceinline__ float bfu(unsigned short u) {
    return __uint_as_float(((unsigned)u) << 16);
}

// ---------------- weight converts ----------------
__global__ void k_cvt(const float* __restrict__ in, bf16* __restrict__ out, int n) {
    int i = blockIdx.x * 256 + threadIdx.x;
    if (i < n) out[i] = __float2bfloat16(in[i]);
}

// W_xh [EMBED][HIDDEN] -> wxh_t [HIDDEN][EMBED] bf16
__global__ void k_txp_wxh(const float* __restrict__ in, bf16* __restrict__ out) {
    int idx = blockIdx.x * 256 + threadIdx.x;   // 65536
    int e = idx >> 9, j = idx & 511;
    out[j * EMBED + e] = __float2bfloat16(in[idx]);
}

// W_hh [K=512][N=512] -> wt [N=512][K=512] bf16
__global__ void k_txp_whh(const float* __restrict__ in, bf16* __restrict__ out) {
    int idx = blockIdx.x * 256 + threadIdx.x;   // 262144
    int k = idx >> 9, n = idx & 511;
    out[n * HIDDEN + k] = __float2bfloat16(in[idx]);
}

// ---------------- bf16 MFMA GEMM:  C[M][N] = A[M][K] * B'[N][K]^T + bias ----------------
// PERMUTE (phase-1 only): write C in the scan's per-thread-contiguous layout.
// scan thread tid of scan-block blk reads uint4 at ((t*4+blk)*1024 + tid)*8:
//   tid = wid*64 + lk*16 + lm ; holds cols {wid*32 + nt*16 + lm}, rows m=lk*4+r,
//   element order nt*4+r.
// GEMM-side: b = wm*32+mt*16+(lane>>4)*4+r -> blk=wm*2+mt, lk=lane>>4, r ;
//   col = n0+wn*32+nt*16+(lane&15) -> wid = (n0>>5)+wn, nt, lm=lane&15.
template<bool GATHER, bool OUT_BF16, bool PERMUTE>
__global__ __launch_bounds__(256) void k_gemm(
    const bf16* __restrict__ A,       // [M][K]; if GATHER: embedding table [VOCAB][K]
    const int*  __restrict__ xtok,    // tokens [BATCH][SEQ] (GATHER only)
    const bf16* __restrict__ B,       // [N][K]
    const float* __restrict__ bias,   // [N]
    float* __restrict__ Cf,
    bf16*  __restrict__ Cb,
    int M, int N, int K)
{
    __shared__ bf16 As[64][72];
    __shared__ bf16 Bs[64][72];
    const int m0 = blockIdx.x * 64, n0 = blockIdx.y * 64;
    const int tid  = threadIdx.x;
    const int lane = tid & 63, wid = tid >> 6;
    const int wm = wid >> 1, wn = wid & 1;
    const int lrow = tid >> 3, lc8 = tid & 7;

    f32x4 acc[2][2] = {};

    for (int k0 = 0; k0 < K; k0 += 64) {
#pragma unroll
        for (int pass = 0; pass < 2; ++pass) {
            int row = pass * 32 + lrow;
            const bf16* asrc;
            if (GATHER) {
                int m = m0 + row;                 // m = t*BATCH + b
                int t = m >> 6, bb = m & 63;
                int tok = xtok[bb * SEQ + t];
                asrc = A + (size_t)tok * K + k0 + lc8 * 8;
            } else {
                asrc = A + (size_t)(m0 + row) * K + k0 + lc8 * 8;
            }
            *reinterpret_cast<uint4*>(&As[row][lc8 * 8]) = *reinterpret_cast<const uint4*>(asrc);
            *reinterpret_cast<uint4*>(&Bs[row][lc8 * 8]) =
                *reinterpret_cast<const uint4*>(B + (size_t)(n0 + row) * K + k0 + lc8 * 8);
        }
        __syncthreads();
#pragma unroll
        for (int kk = 0; kk < 2; ++kk) {
            bf16x8 af[2], bg[2];
#pragma unroll
            for (int mt = 0; mt < 2; ++mt)
                af[mt] = *reinterpret_cast<const bf16x8*>(
                    &As[wm * 32 + mt * 16 + (lane & 15)][kk * 32 + (lane >> 4) * 8]);
#pragma unroll
            for (int nt = 0; nt < 2; ++nt)
                bg[nt] = *reinterpret_cast<const bf16x8*>(
                    &Bs[wn * 32 + nt * 16 + (lane & 15)][kk * 32 + (lane >> 4) * 8]);
#pragma unroll
            for (int mt = 0; mt < 2; ++mt)
#pragma unroll
                for (int nt = 0; nt < 2; ++nt)
                    acc[mt][nt] = __builtin_amdgcn_mfma_f32_16x16x32_bf16(
                        af[mt], bg[nt], acc[mt][nt], 0, 0, 0);
        }
        __syncthreads();
    }
    if (PERMUTE) {
        const int t = m0 >> 6;
        const int wid_s = (n0 >> 5) + wn;
#pragma unroll
        for (int mt = 0; mt < 2; ++mt) {
            int blk = wm * 2 + mt;
            bf16 tmp[8];
#pragma unroll
            for (int nt = 0; nt < 2; ++nt) {
                int col = n0 + wn * 32 + nt * 16 + (lane & 15);
                float bv = bias[col];
#pragma unroll
                for (int r = 0; r < 4; ++r)
                    tmp[nt * 4 + r] = __float2bfloat16(acc[mt][nt][r] + bv);
            }
            size_t off = ((size_t)(t * 4 + blk) * 1024 +
                          wid_s * 64 + (lane >> 4) * 16 + (lane & 15)) * 8;
            *reinterpret_cast<uint4*>(Cb + off) = *reinterpret_cast<uint4*>(tmp);
        }
    } else {
#pragma unroll
        for (int mt = 0; mt < 2; ++mt) {
            int rbase = m0 + wm * 32 + mt * 16 + (lane >> 4) * 4;
#pragma unroll
            for (int nt = 0; nt < 2; ++nt) {
                int col = n0 + wn * 32 + nt * 16 + (lane & 15);
                float bv = bias[col];
#pragma unroll
                for (int r = 0; r < 4; ++r) {
                    float v = acc[mt][nt][r] + bv;
                    size_t off = (size_t)(rbase + r) * N + col;
                    if (OUT_BF16) Cb[off] = __float2bfloat16(v);
                    else          Cf[off] = v;
                }
            }
        }
    }
}

// ---------------- MFMA scan: 4 blocks x 16 rows, 16 waves x 32 N-cols each ----------------
// 16 k-chunks of 32: 0..2 LDS-resident, 3..10 register-resident (64 VGPR/wave),
// 11..15 streamed from L2 (160 KB/step/CU). 4 waves/SIMD for latency hiding.
#define ROWS 16
#define CHK_LDS 3
#define CHK_REG 8
#define WRES_STRIDE (CHK_LDS * 32 + 8)   // 104
#define H_STRIDE (HIDDEN + 8)            // 520

__global__ __launch_bounds__(1024, 4) void k_scan_mfma(
    const bf16* __restrict__ xwp,   // permuted [SEQ*4][1024 tid][8]
    const bf16* __restrict__ wt,    // [HIDDEN n][HIDDEN k]
    const float* __restrict__ h0,   // [BATCH][HIDDEN]
    bf16* __restrict__ hh,          // [BATCH][SEQ][HIDDEN]
    float* __restrict__ hfin)       // [BATCH][HIDDEN]
{
    __shared__ bf16 wres[HIDDEN * WRES_STRIDE];   // 106.5 KB
    __shared__ bf16 h_lds[2][ROWS * H_STRIDE];    // 2 x 16.6 KB

    const int tid  = threadIdx.x;
    const int lane = tid & 63, wid = tid >> 6;    // 16 waves
    const int b0   = blockIdx.x * ROWS;
    const int scol = wid * 32;                    // wave's 32-col slice
    const int lm   = lane & 15, lk = lane >> 4;

    // ---- one-time: LDS-resident W chunk rows (2 threads per n-row) ----
    {
        int row = tid >> 1, half = tid & 1;
        const bf16* src = wt + (size_t)row * HIDDEN + half * 48;
        bf16* dst = &wres[row * WRES_STRIDE + half * 48];
#pragma unroll
        for (int j = 0; j < 6; ++j)
            *reinterpret_cast<uint4*>(dst + j * 8) =
                *reinterpret_cast<const uint4*>(src + j * 8);
    }
    // ---- one-time: h0 -> h_lds[0] ----
    {
        int row = tid >> 6, c = (tid & 63) * 8;
        const float* src = h0 + (size_t)(b0 + row) * HIDDEN + c;
        bf16 tmp[8];
#pragma unroll
        for (int j = 0; j < 8; ++j) tmp[j] = __float2bfloat16(src[j]);
        *reinterpret_cast<uint4*>(&h_lds[0][row * H_STRIDE + c]) =
            *reinterpret_cast<uint4*>(&tmp[0]);
    }

    // ---- one-time: register-resident B fragments (64 VGPR/wave), pinned ----
    bf16x8 breg[CHK_REG][2];
#pragma unroll
    for (int c = 0; c < CHK_REG; ++c)
#pragma unroll
        for (int nt = 0; nt < 2; ++nt) {
            breg[c][nt] = *reinterpret_cast<const bf16x8*>(
                wt + (size_t)(scol + nt * 16 + lm) * HIDDEN + (CHK_LDS + c) * 32 + lk * 8);
            asm volatile("" : "+v"(breg[c][nt]));   // opaque: no remat
        }

    const bf16* grow[2];
    const bf16* lrowp[2];
#pragma unroll
    for (int nt = 0; nt < 2; ++nt) {
        int row = scol + nt * 16 + lm;
        grow[nt]  = wt + (size_t)row * HIDDEN + lk * 8;
        lrowp[nt] = &wres[row * WRES_STRIDE + lk * 8];
    }

    const int srow = tid >> 6, sc = (tid & 63) * 8;   // hh store slots (8 bf16/thread)

    __syncthreads();

    int p = 0;
    for (int t = 0; t < SEQ; ++t) {
        // store h(t-1) -> hh (vectorized; h_lds[p] complete since last barrier)
        if (t > 0) {
            uint4 v0 = *reinterpret_cast<const uint4*>(&h_lds[p][srow * H_STRIDE + sc]);
            bf16* dst = hh + ((size_t)(b0 + srow) * SEQ + (t - 1)) * HIDDEN + sc;
            *reinterpret_cast<uint4*>(dst) = v0;
        }

        // xw for this step: one uint4 (8 bf16) per thread
        ushort xe[8];
        *reinterpret_cast<uint4*>(&xe[0]) =
            *(reinterpret_cast<const uint4*>(xwp) +
              (size_t)(t * 4 + blockIdx.x) * 1024 + tid);

        f32x4 acc[2] = {};
#pragma unroll
        for (int kc = 0; kc < 16; ++kc) {
            bf16x8 af = *reinterpret_cast<const bf16x8*>(
                &h_lds[p][lm * H_STRIDE + kc * 32 + lk * 8]);
#pragma unroll
            for (int nt = 0; nt < 2; ++nt) {
                bf16x8 bg;
                if (kc < CHK_LDS)
                    bg = *reinterpret_cast<const bf16x8*>(lrowp[nt] + kc * 32);
                else if (kc < CHK_LDS + CHK_REG)
                    bg = breg[kc - CHK_LDS][nt];
                else
                    bg = *reinterpret_cast<const bf16x8*>(grow[nt] + kc * 32);
                acc[nt] = __builtin_amdgcn_mfma_f32_16x16x32_bf16(af, bg, acc[nt], 0, 0, 0);
            }
        }

        // epilogue: h_new -> other h buffer (D map: col=lane&15, row=(lane>>4)*4+r)
#pragma unroll
        for (int nt = 0; nt < 2; ++nt) {
            int col = scol + nt * 16 + lm;
#pragma unroll
            for (int r = 0; r < 4; ++r) {
                int m = lk * 4 + r;
                float pre = acc[nt][r] + bfu(xe[nt * 4 + r]);
                float e2  = __expf(2.f * pre);
                float hn  = 1.f - 2.f / (e2 + 1.f);     // tanh(pre)
                h_lds[p ^ 1][m * H_STRIDE + col] = __float2bfloat16(hn);
                if (t == SEQ - 1) hfin[(size_t)(b0 + m) * HIDDEN + col] = hn;
            }
        }
        p ^= 1;
        __syncthreads();    // single barrier per step
    }

    // final hh row store: h(SEQ-1) lives in h_lds[p]
    {
        uint4 v0 = *reinterpret_cast<const uint4*>(&h_lds[p][srow * H_STRIDE + sc]);
        bf16* dst = hh + ((size_t)(b0 + srow) * SEQ + (SEQ - 1)) * HIDDEN + sc;
        *reinterpret_cast<uint4*>(dst) = v0;
    }
}

// ---------------- launch ----------------
extern "C" void kernel_launch(void* const* d_in, const int* in_sizes, int n_in,
                              void* d_out, int out_size, void* d_ws, size_t ws_size,
                              hipStream_t stream) {
    const int*   x    = (const int*)  d_in[0];
    const float* h0   = (const float*)d_in[1];
    const float* emb  = (const float*)d_in[2];
    const float* wxh  = (const float*)d_in[3];
    const float* whh  = (const float*)d_in[4];
    const float* bh   = (const float*)d_in[5];
    const float* whyw = (const float*)d_in[6];
    const float* whyb = (const float*)d_in[7];

    float* logits = (float*)d_out;                            // [BATCH][SEQ][VOCAB]
    float* hfin   = logits + (size_t)BATCH * SEQ * VOCAB;     // [BATCH][HIDDEN]

    char* p = (char*)d_ws;
    bf16* xwp    = (bf16*)p; p += (size_t)SEQ * BATCH * HIDDEN * 2;
    bf16* hh     = (bf16*)p; p += (size_t)BATCH * SEQ * HIDDEN * 2;
    bf16* wt     = (bf16*)p; p += (size_t)HIDDEN * HIDDEN * 2;
    bf16* wxh_t  = (bf16*)p; p += (size_t)HIDDEN * EMBED * 2;
    bf16* emb_bf = (bf16*)p; p += (size_t)VOCAB * EMBED * 2;
    bf16* why_bf = (bf16*)p; p += (size_t)VOCAB * HIDDEN * 2;

    k_txp_whh<<<(HIDDEN * HIDDEN + 255) / 256, 256, 0, stream>>>(whh, wt);
    k_cvt<<<(VOCAB * EMBED + 255) / 256, 256, 0, stream>>>(emb, emb_bf, VOCAB * EMBED);
    k_cvt<<<(VOCAB * HIDDEN + 255) / 256, 256, 0, stream>>>(whyw, why_bf, VOCAB * HIDDEN);
    k_txp_wxh<<<(EMBED * HIDDEN + 255) / 256, 256, 0, stream>>>(wxh, wxh_t);

    // phase 1: xwp = permute(emb[x] @ W_xh + b_h)
    k_gemm<true, true, true><<<dim3((SEQ * BATCH) / 64, HIDDEN / 64), 256, 0, stream>>>(
        emb_bf, x, wxh_t, bh, nullptr, xwp, SEQ * BATCH, HIDDEN, EMBED);

    // phase 2: the recurrence (4 blocks x 16 batch rows, 1024 threads)
    k_scan_mfma<<<BATCH / ROWS, 1024, 0, stream>>>(xwp, wt, h0, hh, hfin);

    // phase 3: logits = hh @ W_hy^T + b
    k_gemm<false, false, false><<<dim3((BATCH * SEQ) / 64, VOCAB / 64), 256, 0, stream>>>(
        hh, nullptr, why_bf, whyb, logits, nullptr, BATCH * SEQ, VOCAB, HIDDEN);
}